// Round 2
// baseline (219.187 us; speedup 1.0000x reference)
//
#include <hip/hip_runtime.h>
#include <math.h>

#define NB 64
#define NQ 900
#define NC 91
#define TB_THR 0.9f
#define TC_THR 0.2f
#define EPSF 1e-9f
#define LGEPS 1e-6f

#define NWG_PER_B 64
#define EDGE_THREADS 256

// ---------------- union-find (lock-free, hooks larger root under smaller) ----
__device__ __forceinline__ int uf_find(int* p, int x) {
    volatile int* vp = (volatile int*)p;
    int px = vp[x];
    while (px != x) { x = px; px = vp[x]; }
    return x;
}

__device__ void uf_unite(int* p, int a, int b) {
    while (true) {
        a = uf_find(p, a);
        b = uf_find(p, b);
        if (a == b) return;
        int hi = a > b ? a : b;
        int lo = a ^ b ^ hi;
        if (atomicCAS(&p[hi], hi, lo) == hi) return;
        a = hi; b = lo;
    }
}

// ---------------- K1: per-row sums/entropy, init parent/cnt/nmulti ----------
__global__ void k_init(const float* __restrict__ logits,
                       float* __restrict__ s, float* __restrict__ ent,
                       int* __restrict__ parent, int* __restrict__ cnt,
                       int* __restrict__ nmulti) {
    int idx = blockIdx.x * blockDim.x + threadIdx.x;
    if (idx == 0) nmulti[0] = 0;
    if (idx >= NB * NQ) return;
    const float* row = logits + (size_t)idx * NC;
    float ssum = 0.f;
    for (int c = 0; c < NC; ++c) {
        float pv = 1.f / (1.f + expf(-row[c]));
        ssum += pv;
    }
    float denom = ssum + EPSF;
    float e = 0.f;
    for (int c = 0; c < NC; ++c) {
        float pv = 1.f / (1.f + expf(-row[c]));
        float q = pv / denom;
        e += q * logf(q + EPSF);
    }
    s[idx] = ssum;
    ent[idx] = e;
    parent[idx] = idx;
    cnt[idx] = 0;
}

// ---------------- K2: pairwise GIoU + gated KL -> union ---------------------
__global__ __launch_bounds__(EDGE_THREADS)
void k_edges(const float* __restrict__ bboxes, const float* __restrict__ logits,
             const float* __restrict__ s, const float* __restrict__ ent,
             int* __restrict__ parent) {
    __shared__ float bx1[NQ], by1[NQ], bx2[NQ], by2[NQ];   // SoA: conflict-free
    int b  = blockIdx.x / NWG_PER_B;
    int wg = blockIdx.x % NWG_PER_B;
    const float4* bb = (const float4*)(bboxes + (size_t)b * NQ * 4);
    for (int i = threadIdx.x; i < NQ; i += EDGE_THREADS) {
        float4 v = bb[i];                    // cx cy w h
        bx1[i] = v.x - 0.5f * v.z;  by1[i] = v.y - 0.5f * v.w;
        bx2[i] = v.x + 0.5f * v.z;  by2[i] = v.y + 0.5f * v.w;
    }
    __syncthreads();

    const long long NP = (long long)NQ * (NQ - 1) / 2;   // 404550
    const int TOT = NWG_PER_B * EDGE_THREADS;            // 16384
    int slot = wg * EDGE_THREADS + threadIdx.x;
    long long chunk = (NP + TOT - 1) / TOT;              // 25
    long long p0 = (long long)slot * chunk;
    if (p0 >= NP) return;
    long long p1 = p0 + chunk; if (p1 > NP) p1 = NP;

    // decode p0 -> (i,j): base(i) = i*(1799-i)/2
    int i = (int)((1799.0 - sqrt(1799.0 * 1799.0 - 8.0 * (double)p0)) * 0.5);
    if (i < 0) i = 0; if (i > NQ - 2) i = NQ - 2;
    while ((long long)(i + 1) * (1799 - (i + 1)) / 2 <= p0) ++i;
    while ((long long)i * (1799 - i) / 2 > p0) --i;
    int j = i + 1 + (int)(p0 - (long long)i * (1799 - i) / 2);

    float ix1 = bx1[i], iy1 = by1[i], ix2 = bx2[i], iy2 = by2[i];
    float ai  = (ix2 - ix1) * (iy2 - iy1);

    for (long long p = p0; p < p1; ++p) {
        float jx1 = bx1[j], jy1 = by1[j], jx2 = bx2[j], jy2 = by2[j];
        float aj = (jx2 - jx1) * (jy2 - jy1);
        float ltx = fmaxf(ix1, jx1), lty = fmaxf(iy1, jy1);
        float rbx = fminf(ix2, jx2), rby = fminf(iy2, jy2);
        float w = fmaxf(rbx - ltx, 0.f), h = fmaxf(rby - lty, 0.f);
        float inter = w * h;
        float uni = ai + aj - inter;
        float iou = inter / (uni + EPSF);
        float ex = fmaxf(fmaxf(ix2, jx2) - fminf(ix1, jx1), 0.f);
        float ey = fmaxf(fmaxf(iy2, jy2) - fminf(iy1, jy1), 0.f);
        float ae = ex * ey;
        float giou = iou - (ae - uni) / (ae + EPSF);
        if (giou > TB_THR) {
            int gi = b * NQ + i, gj = b * NQ + j;
            const float* li = logits + (size_t)gi * NC;
            const float* lj = logits + (size_t)gj * NC;
            float di = s[gi] + EPSF, dj = s[gj] + EPSF;
            float dotij = 0.f, dotji = 0.f;
            for (int c = 0; c < NC; ++c) {
                float pi = 1.f / (1.f + expf(-li[c]));
                float pj = 1.f / (1.f + expf(-lj[c]));
                float qi = pi / di, qj = pj / dj;
                float lqi = logf(qi + EPSF), lqj = logf(qj + EPSF);
                dotij += qi * lqj;
                dotji += qj * lqi;
            }
            bool edge = (ent[gi] - dotij < TC_THR) || (ent[gj] - dotji < TC_THR);
            if (edge) uf_unite(parent, gi, gj);
        }
        if (++j == NQ) {
            ++i; j = i + 1;
            ix1 = bx1[i]; iy1 = by1[i]; ix2 = bx2[i]; iy2 = by2[i];
            ai = (ix2 - ix1) * (iy2 - iy1);
        }
    }
}

// ---------------- K3: flatten labels, count component sizes -----------------
__global__ void k_flatten(const int* __restrict__ parent,
                          int* __restrict__ label, int* __restrict__ cnt) {
    int idx = blockIdx.x * blockDim.x + threadIdx.x;
    if (idx >= NB * NQ) return;
    int r = idx;
    while (parent[r] != r) r = parent[r];
    label[idx] = r;
    atomicAdd(&cnt[r], 1);
}

// ---------------- K4: compact list of multi-member roots --------------------
__global__ void k_multi(const int* __restrict__ label, const int* __restrict__ cnt,
                        int* __restrict__ nmulti, int* __restrict__ mlist) {
    int idx = blockIdx.x * blockDim.x + threadIdx.x;
    if (idx >= NB * NQ) return;
    if (label[idx] == idx && cnt[idx] > 1) {
        int pos = atomicAdd(nmulti, 1);
        mlist[pos] = idx;
    }
}

// ---------------- K5: gather/finalize (all rows except multi-roots) ---------
__global__ void k_out(const float* __restrict__ bboxes,
                      const float* __restrict__ logits,
                      const int* __restrict__ label, const int* __restrict__ cnt,
                      float* __restrict__ out) {
    long long idx = (long long)blockIdx.x * blockDim.x + threadIdx.x;
    const long long NBB = (long long)NB * NQ * 4;          // 230400
    const long long NTOT = NBB + (long long)NB * NQ * NC;  // 5472000
    if (idx >= NTOT) return;
    if (idx < NBB) {
        int g = (int)(idx >> 2);
        int r = label[g];
        if (r != g) { out[idx] = 0.f; return; }
        if (cnt[g] == 1) out[idx] = bboxes[idx];
        // multi-root: k_sparse writes it
    } else {
        long long t = idx - NBB;
        int g = (int)(t / NC);
        int r = label[g];
        if (r != g) {
            float v = LGEPS;   // prob 0 clipped
            out[idx] = logf(v) - log1pf(-v);
            return;
        }
        if (cnt[g] == 1) {
            float pv = 1.f / (1.f + expf(-logits[t]));
            pv = fminf(fmaxf(pv, LGEPS), 1.f - LGEPS);
            out[idx] = logf(pv) - log1pf(-pv);
        }
        // multi-root: k_sparse writes it
    }
}

// ---------------- K6: sparse multi-member clusters (1 wave per root) --------
__global__ __launch_bounds__(64)
void k_sparse(const float* __restrict__ bboxes, const float* __restrict__ logits,
              const int* __restrict__ label, const int* __restrict__ cnt,
              const int* __restrict__ nmulti, const int* __restrict__ mlist,
              float* __restrict__ out) {
    const long long NBB = (long long)NB * NQ * 4;
    int nm = nmulti[0];
    int lane = threadIdx.x;
    for (int m = blockIdx.x; m < nm; m += gridDim.x) {
        int r = mlist[m];
        int b = r / NQ;
        int base = b * NQ;
        float acc0 = 0.f, acc1 = 0.f, accb = 0.f;
        for (int row = 0; row < NQ; ++row) {
            int g = base + row;
            if (label[g] == r) {
                const float* lr = logits + (size_t)g * NC;
                if (lane < NC)      acc0 += 1.f / (1.f + expf(-lr[lane]));
                if (lane + 64 < NC) acc1 += 1.f / (1.f + expf(-lr[lane + 64]));
                if (lane < 4)       accb += bboxes[(size_t)g * 4 + lane];
            }
        }
        float d = fmaxf((float)cnt[r], 1.f);
        if (lane < 4) out[(size_t)r * 4 + lane] = accb / d;
        if (lane < NC) {
            float v = fminf(fmaxf(acc0 / d, LGEPS), 1.f - LGEPS);
            out[NBB + (size_t)r * NC + lane] = logf(v) - log1pf(-v);
        }
        if (lane + 64 < NC) {
            float v = fminf(fmaxf(acc1 / d, LGEPS), 1.f - LGEPS);
            out[NBB + (size_t)r * NC + lane + 64] = logf(v) - log1pf(-v);
        }
    }
}

extern "C" void kernel_launch(void* const* d_in, const int* in_sizes, int n_in,
                              void* d_out, int out_size, void* d_ws, size_t ws_size,
                              hipStream_t stream) {
    const float* bboxes = (const float*)d_in[0];   // [64,900,4] f32
    const float* logits = (const float*)d_in[1];   // [64,900,91] f32
    float* out = (float*)d_out;

    char* ws = (char*)d_ws;
    const int NROWS = NB * NQ;                     // 57600
    float* s      = (float*)(ws);
    float* ent    = (float*)(ws + 1 * NROWS * 4);
    int*   parent = (int*)  (ws + 2 * NROWS * 4);
    int*   label  = (int*)  (ws + 3 * NROWS * 4);
    int*   cnt    = (int*)  (ws + 4 * NROWS * 4);
    int*   nmulti = (int*)  (ws + 5 * NROWS * 4);
    int*   mlist  = (int*)  (ws + 5 * NROWS * 4 + 256);

    const int TB = 256;
    int rowBlocks = (NROWS + TB - 1) / TB;         // 225
    k_init<<<rowBlocks, TB, 0, stream>>>(logits, s, ent, parent, cnt, nmulti);

    k_edges<<<NB * NWG_PER_B, EDGE_THREADS, 0, stream>>>(bboxes, logits, s, ent, parent);

    k_flatten<<<rowBlocks, TB, 0, stream>>>(parent, label, cnt);

    k_multi<<<rowBlocks, TB, 0, stream>>>(label, cnt, nmulti, mlist);

    const long long NTOT = (long long)NB * NQ * (4 + NC);   // 5472000
    int oBlocks = (int)((NTOT + TB - 1) / TB);
    k_out<<<oBlocks, TB, 0, stream>>>(bboxes, logits, label, cnt, out);

    k_sparse<<<256, 64, 0, stream>>>(bboxes, logits, label, cnt, nmulti, mlist, out);
}

// Round 3
// 82.047 us; speedup vs baseline: 2.6715x; 2.6715x over previous
//
#include <hip/hip_runtime.h>
#include <math.h>

#define NB 64
#define NQ 900
#define NC 91
#define TB_THR 0.9f
#define TC_THR 0.2f
#define EPSF 1e-9f
#define LGEPS 1e-6f

#define TPB 256
#define JT 60                       // j-tile width (900 = 15*60)
#define NSL 15                      // slices per batch
#define EDGE_BLOCKS (NB * NSL)      // 960
#define INIT_BLOCKS 225             // 57600/256
#define SP_BLOCKS 225               // 900 waves @ 4/block
#define OUT_BLOCKS 21375            // 5472000/256

// ---------------- union-find (lock-free, min-index root) --------------------
__device__ __forceinline__ int uf_find(int* p, int x) {
    volatile int* vp = (volatile int*)p;
    int px = vp[x];
    while (px != x) { x = px; px = vp[x]; }
    return x;
}

__device__ void uf_unite(int* p, int a, int b) {
    while (true) {
        a = uf_find(p, a);
        b = uf_find(p, b);
        if (a == b) return;
        int hi = a > b ? a : b;
        int lo = a ^ b ^ hi;
        if (atomicCAS(&p[hi], hi, lo) == hi) return;
        a = hi; b = lo;
    }
}

// ---------------- L1: GIoU candidate sweep + parent/cnt init ----------------
__global__ __launch_bounds__(TPB)
void k_edges_init(const float* __restrict__ bboxes,
                  int* __restrict__ parent, int* __restrict__ cnt,
                  int* __restrict__ ncand, int2* __restrict__ cand, int cap) {
    __shared__ float4 jb[JT];       // xyxy of the j-tile
    int bid = blockIdx.x;
    if (bid >= EDGE_BLOCKS) {
        int idx = (bid - EDGE_BLOCKS) * TPB + threadIdx.x;
        if (idx < NB * NQ) { parent[idx] = idx; cnt[idx] = 0; }
        return;
    }
    int b = bid / NSL, s = bid % NSL;
    int j0 = s * JT;
    int lim = j0 + JT;              // rows i < lim participate (i < j < lim)
    const float4* bb = (const float4*)(bboxes + (size_t)b * NQ * 4);
    if (threadIdx.x < JT) {
        float4 v = bb[j0 + threadIdx.x];   // cx cy w h
        jb[threadIdx.x] = make_float4(v.x - 0.5f * v.z, v.y - 0.5f * v.w,
                                      v.x + 0.5f * v.z, v.y + 0.5f * v.w);
    }
    __syncthreads();
    if ((int)threadIdx.x >= lim) return;   // whole-wave exit past the triangle

    // up to 4 rows per thread, fully unrolled, compile-time indexed
    float rx1[4], ry1[4], rx2[4], ry2[4], ra[4];
#pragma unroll
    for (int k = 0; k < 4; ++k) {
        int i = threadIdx.x + k * TPB;
        int il = i < NQ ? i : NQ - 1;      // clamped load; dead rows predicated later
        float4 v = bb[il];
        float x1 = v.x - 0.5f * v.z, y1 = v.y - 0.5f * v.w;
        float x2 = v.x + 0.5f * v.z, y2 = v.y + 0.5f * v.w;
        rx1[k] = x1; ry1[k] = y1; rx2[k] = x2; ry2[k] = y2;
        ra[k] = (x2 - x1) * (y2 - y1);
    }

    for (int jj = 0; jj < JT; ++jj) {
        int j = j0 + jj;
        float4 B = jb[jj];                 // broadcast read (same addr all lanes)
        float aj = (B.z - B.x) * (B.w - B.y);
#pragma unroll
        for (int k = 0; k < 4; ++k) {
            int i = threadIdx.x + k * TPB;
            if (i < j) {                   // predicated (i<j => i<lim<=NQ)
                float ltx = fmaxf(rx1[k], B.x), lty = fmaxf(ry1[k], B.y);
                float rbx = fminf(rx2[k], B.z), rby = fminf(ry2[k], B.w);
                float w = fmaxf(rbx - ltx, 0.f), h = fmaxf(rby - lty, 0.f);
                float inter = w * h;
                float uni = ra[k] + aj - inter;
                float ex = fmaxf(fmaxf(rx2[k], B.z) - fminf(rx1[k], B.x), 0.f);
                float ey = fmaxf(fmaxf(ry2[k], B.w) - fminf(ry1[k], B.y), 0.f);
                float ae = ex * ey;
                float U = uni + EPSF, A = ae + EPSF;
                // giou > 0.9  <=>  inter*A - (ae-uni)*U > 0.9*U*A   (U,A > 0)
                float lhs = inter * A - (ae - uni) * U;
                float rhs = TB_THR * U * A;
                if (lhs > rhs) {
                    int pos = atomicAdd(ncand, 1);
                    if (pos < cap) cand[pos] = make_int2(b * NQ + i, b * NQ + j);
                }
            }
        }
    }
}

// ---------------- L2: one wave per candidate pair — KL test + union ---------
__global__ __launch_bounds__(TPB)
void k_kl(const float* __restrict__ logits, const int* __restrict__ ncand,
          const int2* __restrict__ cand, int cap, int* __restrict__ parent) {
    int n = *ncand; if (n > cap) n = cap;
    int wid  = (int)((blockIdx.x * TPB + threadIdx.x) >> 6);
    int lane = threadIdx.x & 63;
    int nw   = (int)((gridDim.x * TPB) >> 6);
    for (int m = wid; m < n; m += nw) {
        int2 pr = cand[m];
        const float* li = logits + (size_t)pr.x * NC;
        const float* lj = logits + (size_t)pr.y * NC;
        int c1 = lane + 64;
        bool h1 = (c1 < NC);
        float pi0 = 1.f / (1.f + expf(-li[lane]));
        float pj0 = 1.f / (1.f + expf(-lj[lane]));
        float pi1 = h1 ? 1.f / (1.f + expf(-li[c1])) : 0.f;
        float pj1 = h1 ? 1.f / (1.f + expf(-lj[c1])) : 0.f;
        float si = pi0 + pi1, sj = pj0 + pj1;
        for (int o = 32; o; o >>= 1) { si += __shfl_xor(si, o); sj += __shfl_xor(sj, o); }
        float di = si + EPSF, dj = sj + EPSF;
        float qi0 = pi0 / di, qi1 = pi1 / di, qj0 = pj0 / dj, qj1 = pj1 / dj;
        float lqi0 = logf(qi0 + EPSF), lqj0 = logf(qj0 + EPSF);
        float lqi1 = h1 ? logf(qi1 + EPSF) : 0.f;
        float lqj1 = h1 ? logf(qj1 + EPSF) : 0.f;
        float ei  = qi0 * lqi0 + (h1 ? qi1 * lqi1 : 0.f);
        float ej  = qj0 * lqj0 + (h1 ? qj1 * lqj1 : 0.f);
        float dij = qi0 * lqj0 + (h1 ? qi1 * lqj1 : 0.f);
        float dji = qj0 * lqi0 + (h1 ? qj1 * lqi1 : 0.f);
        for (int o = 32; o; o >>= 1) {
            ei  += __shfl_xor(ei, o);  ej  += __shfl_xor(ej, o);
            dij += __shfl_xor(dij, o); dji += __shfl_xor(dji, o);
        }
        bool edge = ((ei - dij) < TC_THR) || ((ej - dji) < TC_THR);
        if (edge && lane == 0) uf_unite(parent, pr.x, pr.y);
    }
}

// ---------------- L3: flatten labels + component sizes ----------------------
__global__ void k_flatten(const int* __restrict__ parent,
                          int* __restrict__ label, int* __restrict__ cnt) {
    int idx = blockIdx.x * blockDim.x + threadIdx.x;
    if (idx >= NB * NQ) return;
    int r = idx;
    while (parent[r] != r) r = parent[r];
    label[idx] = r;
    atomicAdd(&cnt[r], 1);
}

// ---------------- L4: output (elements) + sparse multi-clusters -------------
__global__ __launch_bounds__(TPB)
void k_out(const float* __restrict__ bboxes, const float* __restrict__ logits,
           const int* __restrict__ label, const int* __restrict__ cnt,
           float* __restrict__ out) {
    const long long NBB  = (long long)NB * NQ * 4;          // 230400
    const long long NTOT = NBB + (long long)NB * NQ * NC;   // 5472000
    int bid = blockIdx.x;
    if (bid < SP_BLOCKS) {
        // 900 waves; wave wv owns rows [wv*64, wv*64+64)
        int wv   = bid * 4 + (threadIdx.x >> 6);
        int lane = threadIdx.x & 63;
        int r0   = wv * 64;
        int r    = r0 + lane;
        bool flag = (label[r] == r) && (cnt[r] > 1);
        unsigned long long mask = __ballot(flag);
        while (mask) {
            int bit = __ffsll((long long)mask) - 1; mask &= mask - 1;
            int R = r0 + bit;
            int b = R / NQ;
            int base = b * NQ;
            float a0 = 0.f, a1 = 0.f, ab = 0.f;
            for (int it = 0; it < 15; ++it) {
                int row = it * 64 + lane;
                bool mem = (row < NQ) && (label[base + row] == R);
                unsigned long long mm = __ballot(mem);
                while (mm) {
                    int mb = __ffsll((long long)mm) - 1; mm &= mm - 1;
                    int g = base + it * 64 + mb;
                    const float* lg = logits + (size_t)g * NC;
                    a0 += 1.f / (1.f + expf(-lg[lane]));
                    if (lane + 64 < NC) a1 += 1.f / (1.f + expf(-lg[lane + 64]));
                    if (lane < 4)       ab += bboxes[(size_t)g * 4 + lane];
                }
            }
            float d = fmaxf((float)cnt[R], 1.f);
            if (lane < 4) out[(size_t)R * 4 + lane] = ab / d;
            {
                float v = fminf(fmaxf(a0 / d, LGEPS), 1.f - LGEPS);
                out[NBB + (size_t)R * NC + lane] = logf(v) - log1pf(-v);
            }
            if (lane + 64 < NC) {
                float v = fminf(fmaxf(a1 / d, LGEPS), 1.f - LGEPS);
                out[NBB + (size_t)R * NC + lane + 64] = logf(v) - log1pf(-v);
            }
        }
        return;
    }
    long long idx = (long long)(bid - SP_BLOCKS) * TPB + threadIdx.x;
    if (idx >= NTOT) return;
    if (idx < NBB) {
        int g = (int)(idx >> 2);
        int r = label[g];
        if (r != g) { out[idx] = 0.f; return; }
        if (cnt[g] == 1) out[idx] = bboxes[idx];
        // multi-root elements written by the sparse path
    } else {
        long long t = idx - NBB;
        int g = (int)(t / NC);
        int r = label[g];
        if (r != g) {
            float v = LGEPS;
            out[idx] = logf(v) - log1pf(-v);
            return;
        }
        if (cnt[g] == 1) {
            float pv = 1.f / (1.f + expf(-logits[t]));
            pv = fminf(fmaxf(pv, LGEPS), 1.f - LGEPS);
            out[idx] = logf(pv) - log1pf(-pv);
        }
    }
}

extern "C" void kernel_launch(void* const* d_in, const int* in_sizes, int n_in,
                              void* d_out, int out_size, void* d_ws, size_t ws_size,
                              hipStream_t stream) {
    const float* bboxes = (const float*)d_in[0];   // [64,900,4] f32
    const float* logits = (const float*)d_in[1];   // [64,900,91] f32
    float* out = (float*)d_out;

    char* ws = (char*)d_ws;
    const int NROWS = NB * NQ;                     // 57600
    int* parent = (int*)(ws);
    int* label  = (int*)(ws + 1 * NROWS * 4);
    int* cnt    = (int*)(ws + 2 * NROWS * 4);
    int* ncand  = (int*)(ws + 3 * NROWS * 4);      // byte 691200
    int2* cand  = (int2*)(ws + 3 * NROWS * 4 + 256);
    size_t base = (size_t)(3 * NROWS * 4 + 256);
    long long cap_ll = ws_size > base ? (long long)((ws_size - base) / sizeof(int2)) : 0;
    int cap = (int)(cap_ll > (1 << 20) ? (1 << 20) : cap_ll);

    hipMemsetAsync(ncand, 0, sizeof(int), stream);

    k_edges_init<<<EDGE_BLOCKS + INIT_BLOCKS, TPB, 0, stream>>>(
        bboxes, parent, cnt, ncand, cand, cap);

    k_kl<<<512, TPB, 0, stream>>>(logits, ncand, cand, cap, parent);

    k_flatten<<<INIT_BLOCKS, TPB, 0, stream>>>(parent, label, cnt);

    k_out<<<SP_BLOCKS + OUT_BLOCKS, TPB, 0, stream>>>(bboxes, logits, label, cnt, out);
}

// Round 6
// 58.041 us; speedup vs baseline: 3.7764x; 1.4136x over previous
//
#include <hip/hip_runtime.h>
#include <math.h>

#define NB 64
#define NQ 900
#define NC 91
#define TB_THR 0.9f
#define TC_THR 0.2f
#define EPSF 1e-9f
#define LGEPS 1e-6f

#define TPB 256
#define TT 120                      // tile side
#define SUB 60                      // rows per lane-slot (2 rows/thread)
#define TPAIRS 36                   // 8*(8+1)/2 tile pairs per batch
#define EDGE_BLOCKS (NB * TPAIRS)   // 2304
#define INIT_BLOCKS 225             // 57600/256
#define SP_BLOCKS 225               // 900 waves @ 4/block
#define OUT4_BLOCKS 5344            // ceil(1368000/256)

// ---------------- union-find (lock-free, min-index root) --------------------
__device__ __forceinline__ int uf_find(int* p, int x) {
    volatile int* vp = (volatile int*)p;
    int px = vp[x];
    while (px != x) { x = px; px = vp[x]; }
    return x;
}

__device__ void uf_unite(int* p, int a, int b) {
    while (true) {
        a = uf_find(p, a);
        b = uf_find(p, b);
        if (a == b) return;
        int hi = a > b ? a : b;
        int lo = a ^ b ^ hi;
        if (atomicCAS(&p[hi], hi, lo) == hi) return;
        a = hi; b = lo;
    }
}

// ---------------- pair test: cheap necessary gate + exact GIoU --------------
__device__ __forceinline__ void do_pair(float4 R, float ai, float4 B, float aj,
                                        bool val, int gi, int gj,
                                        int* __restrict__ ncand,
                                        int2* __restrict__ cand, int cap) {
    float ltx = fmaxf(R.x, B.x), lty = fmaxf(R.y, B.y);
    float rbx = fminf(R.z, B.z), rby = fminf(R.w, B.w);
    float w = fmaxf(rbx - ltx, 0.f), h = fmaxf(rby - lty, 0.f);
    float inter = w * h;
    float uni = ai + aj - inter;
    // giou > 0.9 => iou > 0.9 => inter > 0.9*(uni+eps)   (cheap gate)
    if (val && inter > TB_THR * (uni + EPSF)) {
        float ex = fmaxf(fmaxf(R.z, B.z) - fminf(R.x, B.x), 0.f);
        float ey = fmaxf(fmaxf(R.w, B.w) - fminf(R.y, B.y), 0.f);
        float ae = ex * ey;
        float iou = inter / (uni + EPSF);
        float giou = iou - (ae - uni) / (ae + EPSF);
        if (giou > TB_THR) {
            int pos = atomicAdd(ncand, 1);
            if (pos < cap) cand[pos] = make_int2(gi, gj);
        }
    }
}

// ---------------- L1: tiled GIoU candidate sweep + parent/cnt init ----------
__global__ __launch_bounds__(TPB)
void k_edges_init(const float* __restrict__ bboxes,
                  int* __restrict__ parent, int* __restrict__ cnt,
                  int* __restrict__ ncand, int2* __restrict__ cand, int cap) {
    __shared__ float4 jb[TT];
    __shared__ float  ja[TT];
    int bid = blockIdx.x;
    if (bid >= EDGE_BLOCKS) {
        int idx = (bid - EDGE_BLOCKS) * TPB + threadIdx.x;
        if (idx < NB * NQ) { parent[idx] = idx; cnt[idx] = 0; }
        return;
    }
    int b = bid / TPAIRS, tp = bid % TPAIRS;
    int tj = (int)((sqrtf(8.f * tp + 1.f) - 1.f) * 0.5f);
    while ((tj + 1) * (tj + 2) / 2 <= tp) ++tj;
    while (tj * (tj + 1) / 2 > tp) --tj;
    int ti = tp - tj * (tj + 1) / 2;          // ti <= tj
    int i0 = ti * TT, j0 = tj * TT;
    const float4* bb = (const float4*)(bboxes + (size_t)b * NQ * 4);

    int jend = NQ - j0; if (jend > TT) jend = TT;
    for (int k = threadIdx.x; k < jend; k += TPB) {
        float4 v = bb[j0 + k];                 // cx cy w h
        float4 e = make_float4(v.x - 0.5f * v.z, v.y - 0.5f * v.w,
                               v.x + 0.5f * v.z, v.y + 0.5f * v.w);
        jb[k] = e;
        ja[k] = (e.z - e.x) * (e.w - e.y);
    }
    __syncthreads();

    int lane = threadIdx.x & 63;
    int wv   = threadIdx.x >> 6;
    bool lv  = lane < SUB;
    int iA = i0 + (lv ? lane : 0);
    int iB = iA + SUB;
    bool vB = lv && (iB < NQ);

    float4 a4 = bb[iA];
    float4 RA = make_float4(a4.x - 0.5f * a4.z, a4.y - 0.5f * a4.w,
                            a4.x + 0.5f * a4.z, a4.y + 0.5f * a4.w);
    float aA = (RA.z - RA.x) * (RA.w - RA.y);
    float4 b4 = bb[vB ? iB : iA];
    float4 RB = make_float4(b4.x - 0.5f * b4.z, b4.y - 0.5f * b4.w,
                            b4.x + 0.5f * b4.z, b4.y + 0.5f * b4.w);
    float aB = (RB.z - RB.x) * (RB.w - RB.y);

    int gbase = b * NQ;
    int jlo = wv * 30, jhi = jlo + 30; if (jhi > jend) jhi = jend;
    for (int jj = jlo; jj < jhi; ++jj) {
        int j = j0 + jj;
        float4 B = jb[jj];
        float aj = ja[jj];
        do_pair(RA, aA, B, aj, lv && (iA < j), gbase + iA, gbase + j, ncand, cand, cap);
        do_pair(RB, aB, B, aj, vB && (iB < j), gbase + iB, gbase + j, ncand, cand, cap);
    }
}

// ---------------- L2: one wave per candidate pair — KL test + union ---------
__global__ __launch_bounds__(TPB)
void k_kl(const float* __restrict__ logits, const int* __restrict__ ncand,
          const int2* __restrict__ cand, int cap, int* __restrict__ parent) {
    int n = *ncand; if (n > cap) n = cap;
    int wid  = (int)((blockIdx.x * TPB + threadIdx.x) >> 6);
    int lane = threadIdx.x & 63;
    int nw   = (int)((gridDim.x * TPB) >> 6);
    for (int m = wid; m < n; m += nw) {
        int2 pr = cand[m];
        const float* li = logits + (size_t)pr.x * NC;
        const float* lj = logits + (size_t)pr.y * NC;
        int c1 = lane + 64;
        bool h1 = (c1 < NC);
        float pi0 = 1.f / (1.f + expf(-li[lane]));
        float pj0 = 1.f / (1.f + expf(-lj[lane]));
        float pi1 = h1 ? 1.f / (1.f + expf(-li[c1])) : 0.f;
        float pj1 = h1 ? 1.f / (1.f + expf(-lj[c1])) : 0.f;
        float si = pi0 + pi1, sj = pj0 + pj1;
        for (int o = 32; o; o >>= 1) { si += __shfl_xor(si, o); sj += __shfl_xor(sj, o); }
        float di = si + EPSF, dj = sj + EPSF;
        float qi0 = pi0 / di, qi1 = pi1 / di, qj0 = pj0 / dj, qj1 = pj1 / dj;
        float lqi0 = logf(qi0 + EPSF), lqj0 = logf(qj0 + EPSF);
        float lqi1 = h1 ? logf(qi1 + EPSF) : 0.f;
        float lqj1 = h1 ? logf(qj1 + EPSF) : 0.f;
        float ei  = qi0 * lqi0 + (h1 ? qi1 * lqi1 : 0.f);
        float ej  = qj0 * lqj0 + (h1 ? qj1 * lqj1 : 0.f);
        float dij = qi0 * lqj0 + (h1 ? qi1 * lqj1 : 0.f);
        float dji = qj0 * lqi0 + (h1 ? qj1 * lqi1 : 0.f);
        for (int o = 32; o; o >>= 1) {
            ei  += __shfl_xor(ei, o);  ej  += __shfl_xor(ej, o);
            dij += __shfl_xor(dij, o); dji += __shfl_xor(dji, o);
        }
        bool edge = ((ei - dij) < TC_THR) || ((ej - dji) < TC_THR);
        if (edge && lane == 0) uf_unite(parent, pr.x, pr.y);
    }
}

// ---------------- L3: flatten labels + component sizes ----------------------
__global__ void k_flatten(const int* __restrict__ parent,
                          int* __restrict__ label, int* __restrict__ cnt) {
    int idx = blockIdx.x * blockDim.x + threadIdx.x;
    if (idx >= NB * NQ) return;
    int r = idx;
    while (parent[r] != r) r = parent[r];
    label[idx] = r;
    atomicAdd(&cnt[r], 1);
}

// ---------------- L4: vectorized output + sparse multi-clusters -------------
__global__ __launch_bounds__(TPB)
void k_out(const float* __restrict__ bboxes, const float* __restrict__ logits,
           const int* __restrict__ label, const int* __restrict__ cnt,
           float* __restrict__ out) {
    const long long NBB  = (long long)NB * NQ * 4;          // 230400
    const long long NTOT = NBB + (long long)NB * NQ * NC;   // 5472000
    const float LO = logf(LGEPS) - log1pf(-LGEPS);          // logit(1e-6)
    const float HI = logf(1.f - LGEPS) - log1pf(-(1.f - LGEPS));
    int bid = blockIdx.x;
    if (bid < SP_BLOCKS) {
        // sparse multi-member clusters: 900 waves scan for multi-roots
        int wv   = bid * 4 + (threadIdx.x >> 6);
        int lane = threadIdx.x & 63;
        int r0   = wv * 64;
        int r    = r0 + lane;
        bool flag = (label[r] == r) && (cnt[r] > 1);
        unsigned long long mask = __ballot(flag);
        while (mask) {
            int bit = __ffsll((long long)mask) - 1; mask &= mask - 1;
            int R = r0 + bit;
            int b = R / NQ;
            int base = b * NQ;
            float a0 = 0.f, a1 = 0.f, ab = 0.f;
            for (int it = 0; it < 15; ++it) {
                int row = it * 64 + lane;
                bool mem = (row < NQ) && (label[base + row] == R);
                unsigned long long mm = __ballot(mem);
                while (mm) {
                    int mb = __ffsll((long long)mm) - 1; mm &= mm - 1;
                    int g = base + it * 64 + mb;
                    const float* lg = logits + (size_t)g * NC;
                    a0 += 1.f / (1.f + expf(-lg[lane]));
                    if (lane + 64 < NC) a1 += 1.f / (1.f + expf(-lg[lane + 64]));
                    if (lane < 4)       ab += bboxes[(size_t)g * 4 + lane];
                }
            }
            float d = fmaxf((float)cnt[R], 1.f);
            if (lane < 4) out[(size_t)R * 4 + lane] = ab / d;
            {
                float v = fminf(fmaxf(a0 / d, LGEPS), 1.f - LGEPS);
                out[NBB + (size_t)R * NC + lane] = logf(v) - log1pf(-v);
            }
            if (lane + 64 < NC) {
                float v = fminf(fmaxf(a1 / d, LGEPS), 1.f - LGEPS);
                out[NBB + (size_t)R * NC + lane + 64] = logf(v) - log1pf(-v);
            }
        }
        return;
    }
    long long q4 = (long long)(bid - SP_BLOCKS) * TPB + threadIdx.x;
    if (q4 >= NTOT / 4) return;
    long long idx = q4 * 4;
    if (idx < NBB) {
        // one float4 == one row's bbox
        int g = (int)(idx >> 2);
        int r = label[g];
        float4 o;
        if (r != g) o = make_float4(0.f, 0.f, 0.f, 0.f);
        else if (cnt[g] == 1) o = ((const float4*)bboxes)[g];
        else return;                           // multi-root: sparse path writes
        ((float4*)out)[q4] = o;
        return;
    }
    long long t = idx - NBB;
    int g0 = (int)(t / NC), g3 = (int)((t + 3) / NC);
    if (g0 == g3) {
        int r = label[g0];
        float4 o;
        if (r != g0) o = make_float4(LO, LO, LO, LO);
        else if (cnt[g0] == 1) {
            // logit(clip(sigmoid(x))) == clamp(x, LO, HI)
            float4 L = *(const float4*)(logits + t);
            o = make_float4(fminf(fmaxf(L.x, LO), HI), fminf(fmaxf(L.y, LO), HI),
                            fminf(fmaxf(L.z, LO), HI), fminf(fmaxf(L.w, LO), HI));
        } else return;
        ((float4*)out)[q4] = o;
    } else {
#pragma unroll
        for (int e = 0; e < 4; ++e) {
            long long te = t + e;
            int g = (int)(te / NC);
            int r = label[g];
            if (r != g) out[idx + e] = LO;
            else if (cnt[g] == 1) out[idx + e] = fminf(fmaxf(logits[te], LO), HI);
            // multi-root: sparse path writes
        }
    }
}

extern "C" void kernel_launch(void* const* d_in, const int* in_sizes, int n_in,
                              void* d_out, int out_size, void* d_ws, size_t ws_size,
                              hipStream_t stream) {
    const float* bboxes = (const float*)d_in[0];   // [64,900,4] f32
    const float* logits = (const float*)d_in[1];   // [64,900,91] f32
    float* out = (float*)d_out;

    char* ws = (char*)d_ws;
    const int NROWS = NB * NQ;                     // 57600
    int* parent = (int*)(ws);
    int* label  = (int*)(ws + 1 * NROWS * 4);
    int* cnt    = (int*)(ws + 2 * NROWS * 4);
    int* ncand  = (int*)(ws + 3 * NROWS * 4);
    int2* cand  = (int2*)(ws + 3 * NROWS * 4 + 256);
    size_t base = (size_t)(3 * NROWS * 4 + 256);
    long long cap_ll = ws_size > base ? (long long)((ws_size - base) / sizeof(int2)) : 0;
    int cap = (int)(cap_ll > (1 << 20) ? (1 << 20) : cap_ll);

    hipMemsetAsync(ncand, 0, sizeof(int), stream);

    k_edges_init<<<EDGE_BLOCKS + INIT_BLOCKS, TPB, 0, stream>>>(
        bboxes, parent, cnt, ncand, cand, cap);

    k_kl<<<512, TPB, 0, stream>>>(logits, ncand, cand, cap, parent);

    k_flatten<<<INIT_BLOCKS, TPB, 0, stream>>>(parent, label, cnt);

    k_out<<<SP_BLOCKS + OUT4_BLOCKS, TPB, 0, stream>>>(bboxes, logits, label, cnt, out);
}

// Round 7
// 57.808 us; speedup vs baseline: 3.7917x; 1.0040x over previous
//
#include <hip/hip_runtime.h>
#include <math.h>

#define NB 64
#define NQ 900
#define NC 91
#define TB_THR 0.9f
#define TC_THR 0.2f
#define EPSF 1e-9f
#define LGEPS 1e-6f

#define TPB 256
#define TT 120                      // tile side
#define SUB 60                      // rows per lane-slot (2 rows/thread)
#define TPAIRS 36                   // 8*(8+1)/2 tile pairs per batch
#define EDGE_BLOCKS (NB * TPAIRS)   // 2304
#define INIT_BLOCKS 225             // 57600/256
#define SP_BLOCKS 225               // 900 waves @ 4/block
#define OUT4_BLOCKS 5344            // ceil(1368000/256)

// ---------------- union-find (lock-free, min-index root) --------------------
__device__ __forceinline__ int uf_find(int* p, int x) {
    volatile int* vp = (volatile int*)p;
    int px = vp[x];
    while (px != x) { x = px; px = vp[x]; }
    return x;
}

__device__ void uf_unite(int* p, int a, int b) {
    while (true) {
        a = uf_find(p, a);
        b = uf_find(p, b);
        if (a == b) return;
        int hi = a > b ? a : b;
        int lo = a ^ b ^ hi;
        if (atomicCAS(&p[hi], hi, lo) == hi) return;
        a = hi; b = lo;
    }
}

// ---------------- K0: clear candidate counter (replaces 40us runtime fill) --
__global__ void k_clear(int* __restrict__ ncand) {
    if (threadIdx.x == 0 && blockIdx.x == 0) *ncand = 0;
}

// ---------------- pair test: cheap necessary gate + exact GIoU --------------
__device__ __forceinline__ void do_pair(float4 R, float ai, float4 B, float aj,
                                        bool val, int gi, int gj,
                                        int* __restrict__ ncand,
                                        int2* __restrict__ cand, int cap) {
    float ltx = fmaxf(R.x, B.x), lty = fmaxf(R.y, B.y);
    float rbx = fminf(R.z, B.z), rby = fminf(R.w, B.w);
    float w = fmaxf(rbx - ltx, 0.f), h = fmaxf(rby - lty, 0.f);
    float inter = w * h;
    float uni = ai + aj - inter;
    // giou > 0.9 => iou > 0.9 => inter > 0.9*(uni+eps)   (cheap gate)
    if (val && inter > TB_THR * (uni + EPSF)) {
        float ex = fmaxf(fmaxf(R.z, B.z) - fminf(R.x, B.x), 0.f);
        float ey = fmaxf(fmaxf(R.w, B.w) - fminf(R.y, B.y), 0.f);
        float ae = ex * ey;
        float iou = inter / (uni + EPSF);
        float giou = iou - (ae - uni) / (ae + EPSF);
        if (giou > TB_THR) {
            int pos = atomicAdd(ncand, 1);
            if (pos < cap) cand[pos] = make_int2(gi, gj);
        }
    }
}

// ---------------- L1: tiled GIoU candidate sweep + parent/cnt init ----------
__global__ __launch_bounds__(TPB)
void k_edges_init(const float* __restrict__ bboxes,
                  int* __restrict__ parent, int* __restrict__ cnt,
                  int* __restrict__ ncand, int2* __restrict__ cand, int cap) {
    __shared__ float4 jb[TT];
    __shared__ float  ja[TT];
    int bid = blockIdx.x;
    if (bid >= EDGE_BLOCKS) {
        int idx = (bid - EDGE_BLOCKS) * TPB + threadIdx.x;
        if (idx < NB * NQ) { parent[idx] = idx; cnt[idx] = 0; }
        return;
    }
    int b = bid / TPAIRS, tp = bid % TPAIRS;
    int tj = (int)((sqrtf(8.f * tp + 1.f) - 1.f) * 0.5f);
    while ((tj + 1) * (tj + 2) / 2 <= tp) ++tj;
    while (tj * (tj + 1) / 2 > tp) --tj;
    int ti = tp - tj * (tj + 1) / 2;          // ti <= tj
    int i0 = ti * TT, j0 = tj * TT;
    const float4* bb = (const float4*)(bboxes + (size_t)b * NQ * 4);

    int jend = NQ - j0; if (jend > TT) jend = TT;
    for (int k = threadIdx.x; k < jend; k += TPB) {
        float4 v = bb[j0 + k];                 // cx cy w h
        float4 e = make_float4(v.x - 0.5f * v.z, v.y - 0.5f * v.w,
                               v.x + 0.5f * v.z, v.y + 0.5f * v.w);
        jb[k] = e;
        ja[k] = (e.z - e.x) * (e.w - e.y);
    }
    __syncthreads();

    int lane = threadIdx.x & 63;
    int wv   = threadIdx.x >> 6;
    bool lv  = lane < SUB;
    int iA = i0 + (lv ? lane : 0);
    int iB = iA + SUB;
    bool vB = lv && (iB < NQ);

    float4 a4 = bb[iA];
    float4 RA = make_float4(a4.x - 0.5f * a4.z, a4.y - 0.5f * a4.w,
                            a4.x + 0.5f * a4.z, a4.y + 0.5f * a4.w);
    float aA = (RA.z - RA.x) * (RA.w - RA.y);
    float4 b4 = bb[vB ? iB : iA];
    float4 RB = make_float4(b4.x - 0.5f * b4.z, b4.y - 0.5f * b4.w,
                            b4.x + 0.5f * b4.z, b4.y + 0.5f * b4.w);
    float aB = (RB.z - RB.x) * (RB.w - RB.y);

    int gbase = b * NQ;
    int jlo = wv * 30, jhi = jlo + 30; if (jhi > jend) jhi = jend;
    for (int jj = jlo; jj < jhi; ++jj) {
        int j = j0 + jj;
        float4 B = jb[jj];
        float aj = ja[jj];
        do_pair(RA, aA, B, aj, lv && (iA < j), gbase + iA, gbase + j, ncand, cand, cap);
        do_pair(RB, aB, B, aj, vB && (iB < j), gbase + iB, gbase + j, ncand, cand, cap);
    }
}

// ---------------- L2: one wave per candidate pair — KL test + union ---------
__global__ __launch_bounds__(TPB)
void k_kl(const float* __restrict__ logits, const int* __restrict__ ncand,
          const int2* __restrict__ cand, int cap, int* __restrict__ parent) {
    int n = *ncand; if (n > cap) n = cap;
    int wid  = (int)((blockIdx.x * TPB + threadIdx.x) >> 6);
    int lane = threadIdx.x & 63;
    int nw   = (int)((gridDim.x * TPB) >> 6);
    for (int m = wid; m < n; m += nw) {
        int2 pr = cand[m];
        const float* li = logits + (size_t)pr.x * NC;
        const float* lj = logits + (size_t)pr.y * NC;
        int c1 = lane + 64;
        bool h1 = (c1 < NC);
        float pi0 = 1.f / (1.f + expf(-li[lane]));
        float pj0 = 1.f / (1.f + expf(-lj[lane]));
        float pi1 = h1 ? 1.f / (1.f + expf(-li[c1])) : 0.f;
        float pj1 = h1 ? 1.f / (1.f + expf(-lj[c1])) : 0.f;
        float si = pi0 + pi1, sj = pj0 + pj1;
        for (int o = 32; o; o >>= 1) { si += __shfl_xor(si, o); sj += __shfl_xor(sj, o); }
        float di = si + EPSF, dj = sj + EPSF;
        float qi0 = pi0 / di, qi1 = pi1 / di, qj0 = pj0 / dj, qj1 = pj1 / dj;
        float lqi0 = logf(qi0 + EPSF), lqj0 = logf(qj0 + EPSF);
        float lqi1 = h1 ? logf(qi1 + EPSF) : 0.f;
        float lqj1 = h1 ? logf(qj1 + EPSF) : 0.f;
        float ei  = qi0 * lqi0 + (h1 ? qi1 * lqi1 : 0.f);
        float ej  = qj0 * lqj0 + (h1 ? qj1 * lqj1 : 0.f);
        float dij = qi0 * lqj0 + (h1 ? qi1 * lqj1 : 0.f);
        float dji = qj0 * lqi0 + (h1 ? qj1 * lqi1 : 0.f);
        for (int o = 32; o; o >>= 1) {
            ei  += __shfl_xor(ei, o);  ej  += __shfl_xor(ej, o);
            dij += __shfl_xor(dij, o); dji += __shfl_xor(dji, o);
        }
        bool edge = ((ei - dij) < TC_THR) || ((ej - dji) < TC_THR);
        if (edge && lane == 0) uf_unite(parent, pr.x, pr.y);
    }
}

// ---------------- L3: flatten labels + component sizes ----------------------
__global__ void k_flatten(const int* __restrict__ parent,
                          int* __restrict__ label, int* __restrict__ cnt) {
    int idx = blockIdx.x * blockDim.x + threadIdx.x;
    if (idx >= NB * NQ) return;
    int r = idx;
    while (parent[r] != r) r = parent[r];
    label[idx] = r;
    atomicAdd(&cnt[r], 1);
}

// ---------------- L4: vectorized output + sparse multi-clusters -------------
__global__ __launch_bounds__(TPB)
void k_out(const float* __restrict__ bboxes, const float* __restrict__ logits,
           const int* __restrict__ label, const int* __restrict__ cnt,
           float* __restrict__ out) {
    const long long NBB  = (long long)NB * NQ * 4;          // 230400
    const long long NTOT = NBB + (long long)NB * NQ * NC;   // 5472000
    const float LO = logf(LGEPS) - log1pf(-LGEPS);          // logit(1e-6)
    const float HI = logf(1.f - LGEPS) - log1pf(-(1.f - LGEPS));
    int bid = blockIdx.x;
    if (bid < SP_BLOCKS) {
        // sparse multi-member clusters: 900 waves scan for multi-roots
        int wv   = bid * 4 + (threadIdx.x >> 6);
        int lane = threadIdx.x & 63;
        int r0   = wv * 64;
        int r    = r0 + lane;
        bool flag = (label[r] == r) && (cnt[r] > 1);
        unsigned long long mask = __ballot(flag);
        while (mask) {
            int bit = __ffsll((long long)mask) - 1; mask &= mask - 1;
            int R = r0 + bit;
            int b = R / NQ;
            int base = b * NQ;
            float a0 = 0.f, a1 = 0.f, ab = 0.f;
            for (int it = 0; it < 15; ++it) {
                int row = it * 64 + lane;
                bool mem = (row < NQ) && (label[base + row] == R);
                unsigned long long mm = __ballot(mem);
                while (mm) {
                    int mb = __ffsll((long long)mm) - 1; mm &= mm - 1;
                    int g = base + it * 64 + mb;
                    const float* lg = logits + (size_t)g * NC;
                    a0 += 1.f / (1.f + expf(-lg[lane]));
                    if (lane + 64 < NC) a1 += 1.f / (1.f + expf(-lg[lane + 64]));
                    if (lane < 4)       ab += bboxes[(size_t)g * 4 + lane];
                }
            }
            float d = fmaxf((float)cnt[R], 1.f);
            if (lane < 4) out[(size_t)R * 4 + lane] = ab / d;
            {
                float v = fminf(fmaxf(a0 / d, LGEPS), 1.f - LGEPS);
                out[NBB + (size_t)R * NC + lane] = logf(v) - log1pf(-v);
            }
            if (lane + 64 < NC) {
                float v = fminf(fmaxf(a1 / d, LGEPS), 1.f - LGEPS);
                out[NBB + (size_t)R * NC + lane + 64] = logf(v) - log1pf(-v);
            }
        }
        return;
    }
    long long q4 = (long long)(bid - SP_BLOCKS) * TPB + threadIdx.x;
    if (q4 >= NTOT / 4) return;
    long long idx = q4 * 4;
    if (idx < NBB) {
        // one float4 == one row's bbox
        int g = (int)(idx >> 2);
        int r = label[g];
        float4 o;
        if (r != g) o = make_float4(0.f, 0.f, 0.f, 0.f);
        else if (cnt[g] == 1) o = ((const float4*)bboxes)[g];
        else return;                           // multi-root: sparse path writes
        ((float4*)out)[q4] = o;
        return;
    }
    long long t = idx - NBB;
    int g0 = (int)(t / NC), g3 = (int)((t + 3) / NC);
    if (g0 == g3) {
        int r = label[g0];
        float4 o;
        if (r != g0) o = make_float4(LO, LO, LO, LO);
        else if (cnt[g0] == 1) {
            // logit(clip(sigmoid(x))) == clamp(x, LO, HI)
            float4 L = *(const float4*)(logits + t);
            o = make_float4(fminf(fmaxf(L.x, LO), HI), fminf(fmaxf(L.y, LO), HI),
                            fminf(fmaxf(L.z, LO), HI), fminf(fmaxf(L.w, LO), HI));
        } else return;
        ((float4*)out)[q4] = o;
    } else {
#pragma unroll
        for (int e = 0; e < 4; ++e) {
            long long te = t + e;
            int g = (int)(te / NC);
            int r = label[g];
            if (r != g) out[idx + e] = LO;
            else if (cnt[g] == 1) out[idx + e] = fminf(fmaxf(logits[te], LO), HI);
            // multi-root: sparse path writes
        }
    }
}

extern "C" void kernel_launch(void* const* d_in, const int* in_sizes, int n_in,
                              void* d_out, int out_size, void* d_ws, size_t ws_size,
                              hipStream_t stream) {
    const float* bboxes = (const float*)d_in[0];   // [64,900,4] f32
    const float* logits = (const float*)d_in[1];   // [64,900,91] f32
    float* out = (float*)d_out;

    char* ws = (char*)d_ws;
    const int NROWS = NB * NQ;                     // 57600
    int* parent = (int*)(ws);
    int* label  = (int*)(ws + 1 * NROWS * 4);
    int* cnt    = (int*)(ws + 2 * NROWS * 4);
    int* ncand  = (int*)(ws + 3 * NROWS * 4);
    int2* cand  = (int2*)(ws + 3 * NROWS * 4 + 256);
    size_t base = (size_t)(3 * NROWS * 4 + 256);
    long long cap_ll = ws_size > base ? (long long)((ws_size - base) / sizeof(int2)) : 0;
    int cap = (int)(cap_ll > (1 << 20) ? (1 << 20) : cap_ll);

    k_clear<<<1, 64, 0, stream>>>(ncand);

    k_edges_init<<<EDGE_BLOCKS + INIT_BLOCKS, TPB, 0, stream>>>(
        bboxes, parent, cnt, ncand, cand, cap);

    k_kl<<<512, TPB, 0, stream>>>(logits, ncand, cand, cap, parent);

    k_flatten<<<INIT_BLOCKS, TPB, 0, stream>>>(parent, label, cnt);

    k_out<<<SP_BLOCKS + OUT4_BLOCKS, TPB, 0, stream>>>(bboxes, logits, label, cnt, out);
}